// Round 4
// baseline (165.726 us; speedup 1.0000x reference)
//
#include <hip/hip_runtime.h>
#include <math.h>

#define D    32
#define PREV 64
#define HID  128
#define HDIM 64
#define NW   2112    // (D+1)*PREV
#define BPB  32      // batches per block

#define MAGIC1 0x1357A5A5u
#define MAGIC2 0x2468C3C3u

// ws float layout:
//   [0,2112)      w1/b1 flat (w1: i<2048 as [d*64+p], b1: last 64)
//   [4096,8192)   M[h*32+d]
//   [8192,12288)  w2T[h*32+d] = w2[d,h]
//   [12288,12416) sbias[h]
//   [12416,12544) c[h]
// flags (u32 indices into (uint*)ws):
//   [13056,13065) w1-done flags (9 blocks)  == MAGIC1
//   [13088,13104) M-done flags (16 blocks)  == MAGIC2
// Magic-value flags are robust to ANY ws initial content (0xAA poison or
// garbage): false-positive needs a 32-bit collision. Grid=256=#CUs ->
// all blocks co-resident (57KB LDS, 256 thr) -> producer blocks always run.

__global__ __launch_bounds__(256) void fused_kernel(
    const float* __restrict__ y,
    const float* __restrict__ t,
    const float* __restrict__ hw1,
    const float* __restrict__ hb1,
    const float* __restrict__ hw2,
    const float* __restrict__ hb2,
    const float* __restrict__ bw,
    const float* __restrict__ bb,
    const float* __restrict__ w2,
    const float* __restrict__ b2,
    float* __restrict__ ws,
    float* __restrict__ out)
{
    __shared__ float xs[BPB][36];
    __shared__ float Ms[HID][36];
    __shared__ float Ws[HID][36];
    __shared__ float os[BPB][33];
    __shared__ float sbias_s[HID];
    __shared__ float cs_s[HID];
    __shared__ float b2s[D];
    __shared__ float hcode[HDIM];
    __shared__ float w1s[D][68];
    __shared__ float b1s[PREV];
    __shared__ float Mt[8][33];

    const int tid = threadIdx.x;
    const int blk = blockIdx.x;
    unsigned* flags1 = reinterpret_cast<unsigned*>(ws) + 13056;
    unsigned* flags2 = reinterpret_cast<unsigned*>(ws) + 13088;

    // ---- Phase 1 (blocks 0..8): distributed w1/b1, one row per thread ----
    if (blk < 9) {
        if (tid < HDIM) hcode[tid] = tanhf(t[0] * hw1[tid] + hb1[tid]);
        __syncthreads();
        const int i = blk * 256 + tid;
        if (i < NW) {
            const float4* row = reinterpret_cast<const float4*>(hw2 + i * HDIM);
            float acc = hb2[i];
            #pragma unroll
            for (int q = 0; q < 16; ++q) {
                float4 u = row[q];
                int j = q * 4;
                acc += u.x * hcode[j] + u.y * hcode[j + 1]
                     + u.z * hcode[j + 2] + u.w * hcode[j + 3];
            }
            ws[i] = acc;
        }
        __syncthreads();
        if (tid == 0)
            __hip_atomic_store(&flags1[blk], MAGIC1,
                               __ATOMIC_RELEASE, __HIP_MEMORY_SCOPE_AGENT);
    }

    // ---- All blocks: stage this block's 32 x-rows (overlaps prep) ----
    for (int idx = tid; idx < BPB * D; idx += 256) {
        int r = idx >> 5, c = idx & 31;
        xs[r][c] = y[(blk * BPB + r) * (D + 1) + c];
    }
    if (tid < D) b2s[tid] = b2[tid];

    // ---- Phase 2 (blocks 0..15): M / sbias / c / w2T for 8 h's each ----
    if (blk < 16) {
        if (tid == 0) {
            for (int j = 0; j < 9; ++j)
                while (__hip_atomic_load(&flags1[j], __ATOMIC_ACQUIRE,
                                         __HIP_MEMORY_SCOPE_AGENT) != MAGIC1)
                    __builtin_amdgcn_s_sleep(1);
        }
        __syncthreads();
        for (int i = tid; i < NW; i += 256) {
            float v = ws[i];
            if (i < D * PREV) w1s[i >> 6][i & 63] = v;
            else              b1s[i - D * PREV] = v;
        }
        __syncthreads();

        const int hsub = tid >> 5, d = tid & 31;
        const int h = blk * 8 + hsub;
        {
            const float4* bwr = reinterpret_cast<const float4*>(bw + h * PREV);
            float acc = 0.f;
            #pragma unroll
            for (int q = 0; q < 16; ++q) {
                float4 u = bwr[q];
                int p = q * 4;
                acc += u.x * w1s[d][p]     + u.y * w1s[d][p + 1]
                     + u.z * w1s[d][p + 2] + u.w * w1s[d][p + 3];
            }
            Mt[hsub][d] = acc;
            ws[4096 + h * D + d] = acc;              // M
            ws[8192 + h * D + d] = w2[d * HID + h];  // w2T
        }
        __syncthreads();
        if (tid < 8) {
            const int hh = blk * 8 + tid;
            float cacc = 0.f;
            #pragma unroll
            for (int dd = 0; dd < D; ++dd)
                cacc += Mt[tid][dd] * w2[dd * HID + hh];
            float sacc = bb[hh];
            #pragma unroll
            for (int p = 0; p < PREV; ++p)
                sacc += b1s[p] * bw[hh * PREV + p];
            ws[12416 + hh] = cacc;   // c
            ws[12288 + hh] = sacc;   // sbias
        }
        __syncthreads();
        if (tid == 0)
            __hip_atomic_store(&flags2[blk], MAGIC2,
                               __ATOMIC_RELEASE, __HIP_MEMORY_SCOPE_AGENT);
    }

    // ---- Phase 3 (all blocks): wait for M, then main loop ----
    if (tid == 0) {
        for (int j = 0; j < 16; ++j)
            while (__hip_atomic_load(&flags2[j], __ATOMIC_ACQUIRE,
                                     __HIP_MEMORY_SCOPE_AGENT) != MAGIC2)
                __builtin_amdgcn_s_sleep(1);
    }
    __syncthreads();

    for (int idx = tid; idx < HID * D; idx += 256) {
        int h = idx >> 5, d = idx & 31;
        Ms[h][d] = ws[4096 + idx];
        Ws[h][d] = ws[8192 + idx];
    }
    if (tid < HID) { sbias_s[tid] = ws[12288 + tid]; cs_s[tid] = ws[12416 + tid]; }
    __syncthreads();

    const int bsub = tid >> 3;   // 0..31: batch within block
    const int hg   = tid & 7;    // 0..7: h-group (owns 16 of 128 h)

    float xr[D];
    const float4* xrow = reinterpret_cast<const float4*>(&xs[bsub][0]);
    #pragma unroll
    for (int q = 0; q < 8; ++q) {
        float4 v = xrow[q];
        xr[4*q] = v.x; xr[4*q+1] = v.y; xr[4*q+2] = v.z; xr[4*q+3] = v.w;
    }

    float dxp[D];
    #pragma unroll
    for (int d = 0; d < D; ++d) dxp[d] = 0.f;
    float divp = 0.f;

    #pragma unroll
    for (int k = 0; k < 16; ++k) {
        const int h = (k << 3) | hg;
        float s = sbias_s[h];
        const float4* mrow = reinterpret_cast<const float4*>(&Ms[h][0]);
        #pragma unroll
        for (int q = 0; q < 8; ++q) {
            float4 m = mrow[q];
            s += xr[4*q]*m.x + xr[4*q+1]*m.y + xr[4*q+2]*m.z + xr[4*q+3]*m.w;
        }
        // tanh(s) = 1 - 2/(e^{2s}+1); exact at both saturations
        float e = __expf(2.f * s);
        float a = 1.f - 2.f / (e + 1.f);
        float g = 1.f - a * a;
        divp += g * cs_s[h];
        const float4* wrow = reinterpret_cast<const float4*>(&Ws[h][0]);
        #pragma unroll
        for (int q = 0; q < 8; ++q) {
            float4 w = wrow[q];
            dxp[4*q]   += a * w.x;
            dxp[4*q+1] += a * w.y;
            dxp[4*q+2] += a * w.z;
            dxp[4*q+3] += a * w.w;
        }
    }

    #pragma unroll
    for (int m = 1; m < 8; m <<= 1) {
        #pragma unroll
        for (int d = 0; d < D; ++d) dxp[d] += __shfl_xor(dxp[d], m, 64);
        divp += __shfl_xor(divp, m, 64);
    }

    if (hg == 0) {
        #pragma unroll
        for (int d = 0; d < D; ++d) os[bsub][d] = dxp[d] + b2s[d];
        os[bsub][D] = -divp;
    }
    __syncthreads();

    const float* osf = &os[0][0];
    float* obase = out + blk * (BPB * (D + 1));
    for (int idx = tid; idx < BPB * (D + 1); idx += 256)
        obase[idx] = osf[idx];
}

extern "C" void kernel_launch(void* const* d_in, const int* in_sizes, int n_in,
                              void* d_out, int out_size, void* d_ws, size_t ws_size,
                              hipStream_t stream) {
    const float* y   = (const float*)d_in[0];
    const float* t   = (const float*)d_in[1];
    const float* hw1 = (const float*)d_in[2];
    const float* hb1 = (const float*)d_in[3];
    const float* hw2 = (const float*)d_in[4];
    const float* hb2 = (const float*)d_in[5];
    const float* bw  = (const float*)d_in[6];
    const float* bb  = (const float*)d_in[7];
    const float* w2  = (const float*)d_in[8];
    const float* b2  = (const float*)d_in[9];
    float* ws  = (float*)d_ws;
    float* out = (float*)d_out;

    hipLaunchKernelGGL(fused_kernel, dim3(256), dim3(256), 0, stream,
                       y, t, hw1, hb1, hw2, hb2, bw, bb, w2, b2, ws, out);
}

// Round 5
// 92.471 us; speedup vs baseline: 1.7922x; 1.7922x over previous
//
#include <hip/hip_runtime.h>
#include <math.h>

#define D    32
#define PREV 64
#define HID  128
#define HDIM 64
#define NW   2112    // (D+1)*PREV
#define BPB  32      // batches per block in main kernel

// ws float layout:
//   [0,4096)     M[h*32+d] = sum_p w1[d,p]*bw[h,p]
//   [4096,4224)  sbias[h]  = b1.bw[h,:] + bb[h]
// Both fully written by prep before main reads them (separate dispatches).

// grid 9 x 256. Blocks 0..7: block b owns d in [4b,4b+4) -> 256 weight rows
// (64 KB hw2 slice, no cross-block redundancy). Block 8: b1 + sbias.
__global__ __launch_bounds__(256) void prep_kernel(
    const float* __restrict__ t,
    const float* __restrict__ hw1,
    const float* __restrict__ hb1,
    const float* __restrict__ hw2,
    const float* __restrict__ hb2,
    const float* __restrict__ bw,
    const float* __restrict__ bb,
    float* __restrict__ ws)
{
    __shared__ float hcode[HDIM];
    __shared__ float w1s[4][64];   // this block's 4 w1 rows [dd][p]
    __shared__ float b1s[PREV];

    const int tid = threadIdx.x;
    const int blk = blockIdx.x;

    if (tid < HDIM) hcode[tid] = tanhf(t[0] * hw1[tid] + hb1[tid]);
    __syncthreads();

    if (blk < 8) {
        // one weight row per thread: i = blk*256+tid = (4*blk + tid/64)*64 + (tid%64)
        const int i = blk * 256 + tid;
        {
            const float4* row = reinterpret_cast<const float4*>(hw2 + (size_t)i * HDIM);
            float acc = hb2[i];
            #pragma unroll
            for (int q = 0; q < 16; ++q) {
                float4 u = row[q];
                int j = q * 4;
                acc += u.x * hcode[j] + u.y * hcode[j + 1]
                     + u.z * hcode[j + 2] + u.w * hcode[j + 3];
            }
            w1s[tid >> 6][tid & 63] = acc;
        }
        __syncthreads();

        // M[h][4b+dd] for all 128 h, dd in [0,4): 512 elements, 2 per thread
        for (int idx = tid; idx < 512; idx += 256) {
            const int h = idx & 127, dd = idx >> 7;
            const float4* bwr = reinterpret_cast<const float4*>(bw + h * PREV);
            const float* w1r = &w1s[dd][0];    // broadcast across lanes
            float acc = 0.f;
            #pragma unroll
            for (int q = 0; q < 16; ++q) {
                float4 u = bwr[q];
                int p = q * 4;
                acc += u.x * w1r[p]     + u.y * w1r[p + 1]
                     + u.z * w1r[p + 2] + u.w * w1r[p + 3];
            }
            ws[h * D + blk * 4 + dd] = acc;
        }
    } else {
        // b1[p] = weights[2048+p]
        if (tid < PREV) {
            const int i = 2048 + tid;
            const float4* row = reinterpret_cast<const float4*>(hw2 + (size_t)i * HDIM);
            float acc = hb2[i];
            #pragma unroll
            for (int q = 0; q < 16; ++q) {
                float4 u = row[q];
                int j = q * 4;
                acc += u.x * hcode[j] + u.y * hcode[j + 1]
                     + u.z * hcode[j + 2] + u.w * hcode[j + 3];
            }
            b1s[tid] = acc;
        }
        __syncthreads();
        // sbias[h]
        if (tid < HID) {
            const float4* bwr = reinterpret_cast<const float4*>(bw + tid * PREV);
            float acc = bb[tid];
            #pragma unroll
            for (int q = 0; q < 16; ++q) {
                float4 u = bwr[q];
                int p = q * 4;
                acc += u.x * b1s[p]     + u.y * b1s[p + 1]
                     + u.z * b1s[p + 2] + u.w * b1s[p + 3];
            }
            ws[4096 + tid] = acc;
        }
    }
}

// grid 256 x 128 threads. Each thread handles 2 batches x 16 h's:
// halves waves/CU -> halves LDS-pipe instruction issue (the round-3 floor).
__global__ __launch_bounds__(128) void main_kernel(
    const float* __restrict__ y,
    const float* __restrict__ ws,
    const float* __restrict__ w2,
    const float* __restrict__ b2,
    float* __restrict__ out)
{
    __shared__ float Ms[HID][36];
    __shared__ float Ws[HID][36];
    __shared__ float xs[BPB][36];
    __shared__ float os[BPB][33];
    __shared__ float sbias_s[HID];
    __shared__ float cs_s[HID];
    __shared__ float b2s[D];

    const int tid = threadIdx.x;
    const int blk = blockIdx.x;

    // stage M (coalesced from ws) and w2^T (coalesced read, transposed write)
    for (int idx = tid; idx < HID * D; idx += 128) {
        int h = idx >> 5, d = idx & 31;
        Ms[h][d] = ws[idx];
    }
    for (int idx = tid; idx < HID * D; idx += 128) {
        int d = idx >> 7, h = idx & 127;
        Ws[h][d] = w2[idx];
    }
    if (tid < HID) sbias_s[tid] = ws[4096 + tid];
    if (tid < D)   b2s[tid] = b2[tid];
    for (int idx = tid; idx < BPB * D; idx += 128) {
        int r = idx >> 5, c = idx & 31;
        xs[r][c] = y[(blk * BPB + r) * (D + 1) + c];
    }
    __syncthreads();

    // c[h] = sum_d M[h,d] * w2[d,h]
    if (tid < HID) {
        float acc = 0.f;
        #pragma unroll
        for (int d = 0; d < D; ++d)
            acc += Ms[tid][d] * Ws[tid][d];
        cs_s[tid] = acc;
    }
    __syncthreads();

    const int bsub2 = tid >> 3;   // 0..15 -> batches 2*bsub2, 2*bsub2+1
    const int hg    = tid & 7;    // 0..7: h-group (owns 16 of 128 h)
    const int b0 = 2 * bsub2, b1 = b0 + 1;

    float xr0[D], xr1[D];
    {
        const float4* x0 = reinterpret_cast<const float4*>(&xs[b0][0]);
        const float4* x1 = reinterpret_cast<const float4*>(&xs[b1][0]);
        #pragma unroll
        for (int q = 0; q < 8; ++q) {
            float4 v0 = x0[q], v1 = x1[q];
            xr0[4*q] = v0.x; xr0[4*q+1] = v0.y; xr0[4*q+2] = v0.z; xr0[4*q+3] = v0.w;
            xr1[4*q] = v1.x; xr1[4*q+1] = v1.y; xr1[4*q+2] = v1.z; xr1[4*q+3] = v1.w;
        }
    }

    float dx0[D], dx1[D];
    #pragma unroll
    for (int d = 0; d < D; ++d) { dx0[d] = 0.f; dx1[d] = 0.f; }
    float div0 = 0.f, div1 = 0.f;

    #pragma unroll
    for (int k = 0; k < 16; ++k) {
        const int h = (k << 3) | hg;
        float s0 = sbias_s[h], s1 = s0;
        const float4* mrow = reinterpret_cast<const float4*>(&Ms[h][0]);
        #pragma unroll
        for (int q = 0; q < 8; ++q) {
            float4 m = mrow[q];
            s0 += xr0[4*q]*m.x + xr0[4*q+1]*m.y + xr0[4*q+2]*m.z + xr0[4*q+3]*m.w;
            s1 += xr1[4*q]*m.x + xr1[4*q+1]*m.y + xr1[4*q+2]*m.z + xr1[4*q+3]*m.w;
        }
        // tanh(s) = 1 - 2/(e^{2s}+1); exact at both saturations
        float e0 = __expf(2.f * s0), e1 = __expf(2.f * s1);
        float a0 = 1.f - 2.f / (e0 + 1.f);
        float a1 = 1.f - 2.f / (e1 + 1.f);
        float ch = cs_s[h];
        div0 += (1.f - a0 * a0) * ch;
        div1 += (1.f - a1 * a1) * ch;
        const float4* wrow = reinterpret_cast<const float4*>(&Ws[h][0]);
        #pragma unroll
        for (int q = 0; q < 8; ++q) {
            float4 w = wrow[q];
            dx0[4*q]   += a0 * w.x;  dx1[4*q]   += a1 * w.x;
            dx0[4*q+1] += a0 * w.y;  dx1[4*q+1] += a1 * w.y;
            dx0[4*q+2] += a0 * w.z;  dx1[4*q+2] += a1 * w.z;
            dx0[4*q+3] += a0 * w.w;  dx1[4*q+3] += a1 * w.w;
        }
    }

    // butterfly reduce over the 8 h-group lanes of each batch pair
    #pragma unroll
    for (int m = 1; m < 8; m <<= 1) {
        #pragma unroll
        for (int d = 0; d < D; ++d) {
            dx0[d] += __shfl_xor(dx0[d], m, 64);
            dx1[d] += __shfl_xor(dx1[d], m, 64);
        }
        div0 += __shfl_xor(div0, m, 64);
        div1 += __shfl_xor(div1, m, 64);
    }

    if (hg == 0) {
        #pragma unroll
        for (int d = 0; d < D; ++d) {
            os[b0][d] = dx0[d] + b2s[d];
            os[b1][d] = dx1[d] + b2s[d];
        }
        os[b0][D] = -div0;
        os[b1][D] = -div1;
    }
    __syncthreads();

    // coalesced store of the block's 32 contiguous output rows (1056 floats)
    const float* osf = &os[0][0];
    float* obase = out + blk * (BPB * (D + 1));
    for (int idx = tid; idx < BPB * (D + 1); idx += 128)
        obase[idx] = osf[idx];
}

extern "C" void kernel_launch(void* const* d_in, const int* in_sizes, int n_in,
                              void* d_out, int out_size, void* d_ws, size_t ws_size,
                              hipStream_t stream) {
    const float* y   = (const float*)d_in[0];
    const float* t   = (const float*)d_in[1];
    const float* hw1 = (const float*)d_in[2];
    const float* hb1 = (const float*)d_in[3];
    const float* hw2 = (const float*)d_in[4];
    const float* hb2 = (const float*)d_in[5];
    const float* bw  = (const float*)d_in[6];
    const float* bb  = (const float*)d_in[7];
    const float* w2  = (const float*)d_in[8];
    const float* b2  = (const float*)d_in[9];
    float* ws  = (float*)d_ws;
    float* out = (float*)d_out;

    hipLaunchKernelGGL(prep_kernel, dim3(9), dim3(256), 0, stream,
                       t, hw1, hb1, hw2, hb2, bw, bb, ws);
    hipLaunchKernelGGL(main_kernel, dim3(8192 / BPB), dim3(128), 0, stream,
                       y, ws, w2, b2, out);
}

// Round 7
// 90.556 us; speedup vs baseline: 1.8301x; 1.0211x over previous
//
#include <hip/hip_runtime.h>
#include <math.h>

#define D    32
#define PREV 64
#define HID  128
#define HDIM 64
#define BPB  32      // batches per block in main kernel

// ws float layout (all regions fully rewritten by prep every call):
//   [0,4096)      M[h*32+d]   = sum_p w1[d,p]*bw[h,p]
//   [4096,4224)   sbias[h]    = b1.bw[h,:] + bb[h]
//   [8192,12288)  w2T[h*32+d] = w2[d,h]   (h-major so main stages conflict-free)

// grid 17 x 128. Blocks 0..15: block b owns d in {2b,2b+1} -> 128 hw2 rows
// (32 KB slice, no cross-block redundancy) -> M columns + w2T columns.
// Block 16: b1 + sbias.
__global__ __launch_bounds__(128) void prep_kernel(
    const float* __restrict__ t,
    const float* __restrict__ hw1,
    const float* __restrict__ hb1,
    const float* __restrict__ hw2,
    const float* __restrict__ hb2,
    const float* __restrict__ bw,
    const float* __restrict__ bb,
    const float* __restrict__ w2,
    float* __restrict__ ws)
{
    __shared__ float hcode[HDIM];
    __shared__ float w1s[2][64];   // this block's 2 w1 rows [dd][p]
    __shared__ float b1s[PREV];

    const int tid = threadIdx.x;
    const int blk = blockIdx.x;

    if (tid < HDIM) hcode[tid] = tanhf(t[0] * hw1[tid] + hb1[tid]);
    __syncthreads();

    if (blk < 16) {
        // one weight row per thread: i = blk*128+tid -> d = i>>6 in {2b,2b+1}
        const int i = blk * 128 + tid;
        {
            const float4* row = reinterpret_cast<const float4*>(hw2 + (size_t)i * HDIM);
            float acc = hb2[i];
            #pragma unroll
            for (int q = 0; q < 16; ++q) {
                float4 u = row[q];
                int j = q * 4;
                acc += u.x * hcode[j] + u.y * hcode[j + 1]
                     + u.z * hcode[j + 2] + u.w * hcode[j + 3];
            }
            w1s[tid >> 6][tid & 63] = acc;
        }
        __syncthreads();

        // M[h][2b+dd] and w2T[h][2b+dd] for all 128 h, dd in {0,1}
        for (int idx = tid; idx < 256; idx += 128) {
            const int h = idx & 127, dd = idx >> 7;
            const int d = 2 * blk + dd;
            const float4* bwr = reinterpret_cast<const float4*>(bw + h * PREV);
            const float* w1r = &w1s[dd][0];   // broadcast across lanes
            float acc = 0.f;
            #pragma unroll
            for (int q = 0; q < 16; ++q) {
                float4 u = bwr[q];
                int p = q * 4;
                acc += u.x * w1r[p]     + u.y * w1r[p + 1]
                     + u.z * w1r[p + 2] + u.w * w1r[p + 3];
            }
            ws[h * D + d] = acc;                    // M
            ws[8192 + h * D + d] = w2[d * HID + h]; // w2T (coalesced read: lanes sweep h)
        }
    } else {
        // blk == 16: b1 then sbias
        if (tid < PREV) {
            const int i = 2048 + tid;
            const float4* row = reinterpret_cast<const float4*>(hw2 + (size_t)i * HDIM);
            float acc = hb2[i];
            #pragma unroll
            for (int q = 0; q < 16; ++q) {
                float4 u = row[q];
                int j = q * 4;
                acc += u.x * hcode[j] + u.y * hcode[j + 1]
                     + u.z * hcode[j + 2] + u.w * hcode[j + 3];
            }
            b1s[tid] = acc;
        }
        __syncthreads();
        {   // sbias[h], one h per thread (128 threads = 128 h)
            const float4* bwr = reinterpret_cast<const float4*>(bw + tid * PREV);
            float acc = bb[tid];
            #pragma unroll
            for (int q = 0; q < 16; ++q) {
                float4 u = bwr[q];
                int p = q * 4;
                acc += u.x * b1s[p]     + u.y * b1s[p + 1]
                     + u.z * b1s[p + 2] + u.w * b1s[p + 3];
            }
            ws[4096 + tid] = acc;
        }
    }
}

// grid 256 x 128 threads. Each thread: 2 batches x 16 h's (halves waves/CU ->
// halves LDS-pipe issue vs 1 batch/thread; proven round 5).
__global__ __launch_bounds__(128) void main_kernel(
    const float* __restrict__ y,
    const float* __restrict__ ws,
    const float* __restrict__ b2,
    float* __restrict__ out)
{
    __shared__ float Ms[HID][36];
    __shared__ float Ws[HID][36];
    __shared__ float xs[BPB][36];
    __shared__ float os[BPB][33];
    __shared__ float sbias_s[HID];
    __shared__ float cs_s[HID];
    __shared__ float b2s[D];

    const int tid = threadIdx.x;
    const int blk = blockIdx.x;

    // stage M and w2T from ws: h=idx>>5 -> 2 rows/wave, d sweeps all 32 banks
    // (conflict-free writes; coalesced global reads)
    for (int idx = tid; idx < HID * D; idx += 128) {
        int h = idx >> 5, d = idx & 31;
        Ms[h][d] = ws[idx];
        Ws[h][d] = ws[8192 + idx];
    }
    sbias_s[tid] = ws[4096 + tid];
    if (tid < D) b2s[tid] = b2[tid];
    for (int idx = tid; idx < BPB * D; idx += 128) {
        int r = idx >> 5, c = idx & 31;
        xs[r][c] = y[(blk * BPB + r) * (D + 1) + c];
    }
    __syncthreads();

    {   // c[h] = sum_d M[h,d]*w2[d,h]; float4 row reads (16 b128/thread)
        const float4* mr = reinterpret_cast<const float4*>(&Ms[tid][0]);
        const float4* wr = reinterpret_cast<const float4*>(&Ws[tid][0]);
        float acc = 0.f;
        #pragma unroll
        for (int q = 0; q < 8; ++q) {
            float4 m = mr[q], w = wr[q];
            acc += m.x * w.x + m.y * w.y + m.z * w.z + m.w * w.w;
        }
        cs_s[tid] = acc;
    }
    __syncthreads();

    const int bsub2 = tid >> 3;   // 0..15 -> batches 2*bsub2, 2*bsub2+1
    const int hg    = tid & 7;    // 0..7: h-group (owns 16 of 128 h)
    const int b0 = 2 * bsub2, b1 = b0 + 1;

    float xr0[D], xr1[D];
    {
        const float4* x0 = reinterpret_cast<const float4*>(&xs[b0][0]);
        const float4* x1 = reinterpret_cast<const float4*>(&xs[b1][0]);
        #pragma unroll
        for (int q = 0; q < 8; ++q) {
            float4 v0 = x0[q], v1 = x1[q];
            xr0[4*q] = v0.x; xr0[4*q+1] = v0.y; xr0[4*q+2] = v0.z; xr0[4*q+3] = v0.w;
            xr1[4*q] = v1.x; xr1[4*q+1] = v1.y; xr1[4*q+2] = v1.z; xr1[4*q+3] = v1.w;
        }
    }

    float dx0[D], dx1[D];
    #pragma unroll
    for (int d = 0; d < D; ++d) { dx0[d] = 0.f; dx1[d] = 0.f; }
    float div0 = 0.f, div1 = 0.f;

    #pragma unroll
    for (int k = 0; k < 16; ++k) {
        const int h = (k << 3) | hg;
        float s0 = sbias_s[h], s1 = s0;
        const float4* mrow = reinterpret_cast<const float4*>(&Ms[h][0]);
        #pragma unroll
        for (int q = 0; q < 8; ++q) {
            float4 m = mrow[q];
            s0 += xr0[4*q]*m.x + xr0[4*q+1]*m.y + xr0[4*q+2]*m.z + xr0[4*q+3]*m.w;
            s1 += xr1[4*q]*m.x + xr1[4*q+1]*m.y + xr1[4*q+2]*m.z + xr1[4*q+3]*m.w;
        }
        // tanh(s) = 1 - 2/(e^{2s}+1); exact at both saturations
        float e0 = __expf(2.f * s0), e1 = __expf(2.f * s1);
        float a0 = 1.f - 2.f / (e0 + 1.f);
        float a1 = 1.f - 2.f / (e1 + 1.f);
        float ch = cs_s[h];
        div0 += (1.f - a0 * a0) * ch;
        div1 += (1.f - a1 * a1) * ch;
        const float4* wrow = reinterpret_cast<const float4*>(&Ws[h][0]);
        #pragma unroll
        for (int q = 0; q < 8; ++q) {
            float4 w = wrow[q];
            dx0[4*q]   += a0 * w.x;  dx1[4*q]   += a1 * w.x;
            dx0[4*q+1] += a0 * w.y;  dx1[4*q+1] += a1 * w.y;
            dx0[4*q+2] += a0 * w.z;  dx1[4*q+2] += a1 * w.z;
            dx0[4*q+3] += a0 * w.w;  dx1[4*q+3] += a1 * w.w;
        }
    }

    // butterfly reduce over the 8 h-group lanes of each batch pair
    #pragma unroll
    for (int m = 1; m < 8; m <<= 1) {
        #pragma unroll
        for (int d = 0; d < D; ++d) {
            dx0[d] += __shfl_xor(dx0[d], m, 64);
            dx1[d] += __shfl_xor(dx1[d], m, 64);
        }
        div0 += __shfl_xor(div0, m, 64);
        div1 += __shfl_xor(div1, m, 64);
    }

    if (hg == 0) {
        #pragma unroll
        for (int d = 0; d < D; ++d) {
            os[b0][d] = dx0[d] + b2s[d];
            os[b1][d] = dx1[d] + b2s[d];
        }
        os[b0][D] = -div0;
        os[b1][D] = -div1;
    }
    __syncthreads();

    // coalesced store of the block's 32 contiguous output rows (1056 floats)
    const float* osf = &os[0][0];
    float* obase = out + blk * (BPB * (D + 1));
    for (int idx = tid; idx < BPB * (D + 1); idx += 128)
        obase[idx] = osf[idx];
}

extern "C" void kernel_launch(void* const* d_in, const int* in_sizes, int n_in,
                              void* d_out, int out_size, void* d_ws, size_t ws_size,
                              hipStream_t stream) {
    const float* y   = (const float*)d_in[0];
    const float* t   = (const float*)d_in[1];
    const float* hw1 = (const float*)d_in[2];
    const float* hb1 = (const float*)d_in[3];
    const float* hw2 = (const float*)d_in[4];
    const float* hb2 = (const float*)d_in[5];
    const float* bw  = (const float*)d_in[6];
    const float* bb  = (const float*)d_in[7];
    const float* w2  = (const float*)d_in[8];
    const float* b2  = (const float*)d_in[9];
    float* ws  = (float*)d_ws;
    float* out = (float*)d_out;

    hipLaunchKernelGGL(prep_kernel, dim3(17), dim3(128), 0, stream,
                       t, hw1, hb1, hw2, hb2, bw, bb, w2, ws);
    hipLaunchKernelGGL(main_kernel, dim3(8192 / BPB), dim3(128), 0, stream,
                       y, ws, b2, out);
}

// Round 8
// 86.007 us; speedup vs baseline: 1.9269x; 1.0529x over previous
//
#include <hip/hip_runtime.h>
#include <math.h>

#define D    32
#define PREV 64
#define HID  128
#define HDIM 64
#define BPB  32      // batches per block in main kernel

// ws float layout (all regions fully rewritten by prep every call):
//   [0,4096)      M[h*32+d]   = sum_p w1[d,p]*bw[h,p]
//   [4096,4224)   sbias[h]    = b1.bw[h,:] + bb[h]
//   [8192,12288)  w2T[h*32+d] = w2[d,h]   (h-major -> main stages with flat float4)

// grid 17 x 128. Blocks 0..15: block b owns d in {2b,2b+1} -> 128 hw2 rows
// (32 KB slice, no cross-block redundancy) -> M columns + w2T columns.
// Block 16: b1 + sbias.
__global__ __launch_bounds__(128) void prep_kernel(
    const float* __restrict__ t,
    const float* __restrict__ hw1,
    const float* __restrict__ hb1,
    const float* __restrict__ hw2,
    const float* __restrict__ hb2,
    const float* __restrict__ bw,
    const float* __restrict__ bb,
    const float* __restrict__ w2,
    float* __restrict__ ws)
{
    __shared__ float hcode[HDIM];
    __shared__ float w1s[2][64];   // this block's 2 w1 rows [dd][p]
    __shared__ float b1s[PREV];

    const int tid = threadIdx.x;
    const int blk = blockIdx.x;

    if (tid < HDIM) hcode[tid] = tanhf(t[0] * hw1[tid] + hb1[tid]);
    __syncthreads();

    if (blk < 16) {
        // one weight row per thread: i = blk*128+tid -> d = i>>6 in {2b,2b+1}
        const int i = blk * 128 + tid;
        {
            const float4* row = reinterpret_cast<const float4*>(hw2 + (size_t)i * HDIM);
            float acc = hb2[i];
            #pragma unroll
            for (int q = 0; q < 16; ++q) {
                float4 u = row[q];
                int j = q * 4;
                acc += u.x * hcode[j] + u.y * hcode[j + 1]
                     + u.z * hcode[j + 2] + u.w * hcode[j + 3];
            }
            w1s[tid >> 6][tid & 63] = acc;
        }
        __syncthreads();

        // M[h][2b+dd] and w2T[h][2b+dd] for all 128 h, dd in {0,1}
        for (int idx = tid; idx < 256; idx += 128) {
            const int h = idx & 127, dd = idx >> 7;
            const int d = 2 * blk + dd;
            const float4* bwr = reinterpret_cast<const float4*>(bw + h * PREV);
            const float* w1r = &w1s[dd][0];   // broadcast across lanes
            float acc = 0.f;
            #pragma unroll
            for (int q = 0; q < 16; ++q) {
                float4 u = bwr[q];
                int p = q * 4;
                acc += u.x * w1r[p]     + u.y * w1r[p + 1]
                     + u.z * w1r[p + 2] + u.w * w1r[p + 3];
            }
            ws[h * D + d] = acc;                    // M
            ws[8192 + h * D + d] = w2[d * HID + h]; // w2T (coalesced read: lanes sweep h)
        }
    } else {
        // blk == 16: b1 then sbias
        if (tid < PREV) {
            const int i = 2048 + tid;
            const float4* row = reinterpret_cast<const float4*>(hw2 + (size_t)i * HDIM);
            float acc = hb2[i];
            #pragma unroll
            for (int q = 0; q < 16; ++q) {
                float4 u = row[q];
                int j = q * 4;
                acc += u.x * hcode[j] + u.y * hcode[j + 1]
                     + u.z * hcode[j + 2] + u.w * hcode[j + 3];
            }
            b1s[tid] = acc;
        }
        __syncthreads();
        {   // sbias[h], one h per thread (128 threads = 128 h)
            const float4* bwr = reinterpret_cast<const float4*>(bw + tid * PREV);
            float acc = bb[tid];
            #pragma unroll
            for (int q = 0; q < 16; ++q) {
                float4 u = bwr[q];
                int p = q * 4;
                acc += u.x * b1s[p]     + u.y * b1s[p + 1]
                     + u.z * b1s[p + 2] + u.w * b1s[p + 3];
            }
            ws[4096 + tid] = acc;
        }
    }
}

// grid 256 x 128 threads. Each thread: 2 batches x 16 h's. All global access
// vectorized to float4 (staging was ~74 scalar loads/thread -> ~21 wide ops).
__global__ __launch_bounds__(128) void main_kernel(
    const float* __restrict__ y,
    const float* __restrict__ ws,
    const float* __restrict__ b2,
    float* __restrict__ out)
{
    __shared__ float Ms[HID][36];
    __shared__ float Ws[HID][36];
    __shared__ float xs[BPB][36];
    __shared__ __align__(16) float os[BPB][33];  // flat 1056 floats, 16B-aligned
    __shared__ float sbias_s[HID];
    __shared__ float cs_s[HID];
    __shared__ float b2s[D];

    const int tid = threadIdx.x;
    const int blk = blockIdx.x;

    // ---- staging, all float4 ----
    // Ms/Ws: flat over 4096 floats = 1024 float4; 8 iters x 128 thr.
    // LDS write Ms[h][4q]: offset 36h+4q -> 16B aligned; <=2 lanes/bank (free).
    {
        const float4* m4 = reinterpret_cast<const float4*>(ws);
        const float4* w4 = reinterpret_cast<const float4*>(ws + 8192);
        #pragma unroll
        for (int it = 0; it < 8; ++it) {
            int i = it * 128 + tid;       // float4 index
            int h = i >> 3;               // (4i)>>5
            int dq = (i & 7) << 2;        // (4i)&31
            *reinterpret_cast<float4*>(&Ms[h][dq]) = m4[i];
            *reinterpret_cast<float4*>(&Ws[h][dq]) = w4[i];
        }
    }
    // y: block slice = 1056 contiguous floats (4224 B, 16B-aligned) = 264 float4
    {
        const float4* yb4 = reinterpret_cast<const float4*>(y + (size_t)blk * BPB * 33);
        for (int i = tid; i < 264; i += 128) {
            float4 v = yb4[i];
            int base = 4 * i;
            int r0 = base / 33, c0 = base - 33 * r0;
            // scatter 4 components into padded xs (col 32 = t-column, harmless)
            float vv[4] = { v.x, v.y, v.z, v.w };
            #pragma unroll
            for (int j = 0; j < 4; ++j) {
                int c = c0 + j, r = r0;
                if (c >= 33) { c -= 33; r += 1; }
                xs[r][c] = vv[j];
            }
        }
    }
    sbias_s[tid] = ws[4096 + tid];
    if (tid < D) b2s[tid] = b2[tid];
    __syncthreads();

    {   // c[h] = sum_d M[h,d]*w2[d,h]; float4 row reads
        const float4* mr = reinterpret_cast<const float4*>(&Ms[tid][0]);
        const float4* wr = reinterpret_cast<const float4*>(&Ws[tid][0]);
        float acc = 0.f;
        #pragma unroll
        for (int q = 0; q < 8; ++q) {
            float4 m = mr[q], w = wr[q];
            acc += m.x * w.x + m.y * w.y + m.z * w.z + m.w * w.w;
        }
        cs_s[tid] = acc;
    }
    __syncthreads();

    const int bsub2 = tid >> 3;   // 0..15 -> batches 2*bsub2, 2*bsub2+1
    const int hg    = tid & 7;    // 0..7: h-group (owns 16 of 128 h)
    const int b0 = 2 * bsub2, b1 = b0 + 1;

    float xr0[D], xr1[D];
    {
        const float4* x0 = reinterpret_cast<const float4*>(&xs[b0][0]);
        const float4* x1 = reinterpret_cast<const float4*>(&xs[b1][0]);
        #pragma unroll
        for (int q = 0; q < 8; ++q) {
            float4 v0 = x0[q], v1 = x1[q];
            xr0[4*q] = v0.x; xr0[4*q+1] = v0.y; xr0[4*q+2] = v0.z; xr0[4*q+3] = v0.w;
            xr1[4*q] = v1.x; xr1[4*q+1] = v1.y; xr1[4*q+2] = v1.z; xr1[4*q+3] = v1.w;
        }
    }

    float dx0[D], dx1[D];
    #pragma unroll
    for (int d = 0; d < D; ++d) { dx0[d] = 0.f; dx1[d] = 0.f; }
    float div0 = 0.f, div1 = 0.f;

    #pragma unroll
    for (int k = 0; k < 16; ++k) {
        const int h = (k << 3) | hg;
        float s0 = sbias_s[h], s1 = s0;
        const float4* mrow = reinterpret_cast<const float4*>(&Ms[h][0]);
        #pragma unroll
        for (int q = 0; q < 8; ++q) {
            float4 m = mrow[q];
            s0 += xr0[4*q]*m.x + xr0[4*q+1]*m.y + xr0[4*q+2]*m.z + xr0[4*q+3]*m.w;
            s1 += xr1[4*q]*m.x + xr1[4*q+1]*m.y + xr1[4*q+2]*m.z + xr1[4*q+3]*m.w;
        }
        // tanh(s) = 1 - 2/(e^{2s}+1); exact at both saturations
        float e0 = __expf(2.f * s0), e1 = __expf(2.f * s1);
        float a0 = 1.f - 2.f / (e0 + 1.f);
        float a1 = 1.f - 2.f / (e1 + 1.f);
        float ch = cs_s[h];
        div0 += (1.f - a0 * a0) * ch;
        div1 += (1.f - a1 * a1) * ch;
        const float4* wrow = reinterpret_cast<const float4*>(&Ws[h][0]);
        #pragma unroll
        for (int q = 0; q < 8; ++q) {
            float4 w = wrow[q];
            dx0[4*q]   += a0 * w.x;  dx1[4*q]   += a1 * w.x;
            dx0[4*q+1] += a0 * w.y;  dx1[4*q+1] += a1 * w.y;
            dx0[4*q+2] += a0 * w.z;  dx1[4*q+2] += a1 * w.z;
            dx0[4*q+3] += a0 * w.w;  dx1[4*q+3] += a1 * w.w;
        }
    }

    // butterfly reduce over the 8 h-group lanes of each batch pair
    #pragma unroll
    for (int m = 1; m < 8; m <<= 1) {
        #pragma unroll
        for (int d = 0; d < D; ++d) {
            dx0[d] += __shfl_xor(dx0[d], m, 64);
            dx1[d] += __shfl_xor(dx1[d], m, 64);
        }
        div0 += __shfl_xor(div0, m, 64);
        div1 += __shfl_xor(div1, m, 64);
    }

    if (hg == 0) {
        #pragma unroll
        for (int d = 0; d < D; ++d) {
            os[b0][d] = dx0[d] + b2s[d];
            os[b1][d] = dx1[d] + b2s[d];
        }
        os[b0][D] = -div0;
        os[b1][D] = -div1;
    }
    __syncthreads();

    // coalesced float4 store of the block's 1056 contiguous output floats
    {
        const float4* os4 = reinterpret_cast<const float4*>(&os[0][0]);
        float4* ob4 = reinterpret_cast<float4*>(out + (size_t)blk * BPB * 33);
        for (int i = tid; i < 264; i += 128)
            ob4[i] = os4[i];
    }
}

extern "C" void kernel_launch(void* const* d_in, const int* in_sizes, int n_in,
                              void* d_out, int out_size, void* d_ws, size_t ws_size,
                              hipStream_t stream) {
    const float* y   = (const float*)d_in[0];
    const float* t   = (const float*)d_in[1];
    const float* hw1 = (const float*)d_in[2];
    const float* hb1 = (const float*)d_in[3];
    const float* hw2 = (const float*)d_in[4];
    const float* hb2 = (const float*)d_in[5];
    const float* bw  = (const float*)d_in[6];
    const float* bb  = (const float*)d_in[7];
    const float* w2  = (const float*)d_in[8];
    const float* b2  = (const float*)d_in[9];
    float* ws  = (float*)d_ws;
    float* out = (float*)d_out;

    hipLaunchKernelGGL(prep_kernel, dim3(17), dim3(128), 0, stream,
                       t, hw1, hb1, hw2, hb2, bw, bb, w2, ws);
    hipLaunchKernelGGL(main_kernel, dim3(8192 / BPB), dim3(128), 0, stream,
                       y, ws, b2, out);
}